// Round 9
// baseline (394.722 us; speedup 1.0000x reference)
//
#include <hip/hip_runtime.h>
#include <hip/hip_bf16.h>

// Conv2d 3x3 s1p1: x(32,128,56,56) f32, w(256,128,3,3) f32, bias(256) -> (32,256,56,56) f32.
// R7 (resubmit; previous round's container failed twice — no data):
// conv_main rebuilt as NO-LDS direct-fragment implicit GEMM.
// Post-mortem arithmetic of R5 showed the LDS port (staging writes + ds_reads ~96 LDS
// instrs/block-stage ~ 53 us of 76) is the binding resource, not barriers — which is why
// both counted-vmcnt pipelines (R4, R6) regressed. MFMA fragments are 16 contiguous bytes
// at computable NHWC addresses -> load A/B frags straight from global (L2) into VGPRs:
// zero LDS, zero barriers. Wave loads form perfect 64 B segments (quad x l15). Intra-block
// 2x duplication is L1-resident (16 KB/stage working set). Wt (2.25 MB) + XCD-local xpad
// slice (~3.4 MB) are L2-resident. 36-step loop fully unrolled; compiler pipelines pure
// global->VGPR loads freely (no barrier to defeat it). prep_x / prep_w unchanged.

#define CIN   128
#define HH    56
#define WW    56
#define COUT  256
#define HW    3136
#define NIMG  32
#define NP    (NIMG * HW)            // 100352 = 784 * 128
#define XPW   58
#define XPIX  (XPW * XPW)            // 3364
#define XPAD_BYTES (NIMG * XPIX * CIN * 2)   // 27,566,080
#define WT_OFF     XPAD_BYTES

typedef __bf16 bf16x8 __attribute__((ext_vector_type(8)));
typedef float  f32x4  __attribute__((ext_vector_type(4)));

// ---- pre-pass 1: x NCHW f32 -> xpad NHWC bf16 with 1-px halo; writes own halo zeros.
__global__ __launch_bounds__(128) void prep_x(const float* __restrict__ x,
                                              __hip_bfloat16* __restrict__ xp) {
    __shared__ unsigned short t[HH * CIN];   // [x][ci], 14336 B
    const int b  = blockIdx.x;               // 32*56
    const int n  = b / HH;
    const int y  = b - n * HH;
    const int ci = threadIdx.x;              // 0..127

    const float* src = x + ((size_t)(n * CIN + ci) * HW) + y * WW;
    #pragma unroll
    for (int j = 0; j < 14; ++j) {           // 56 floats, per-lane contiguous stream
        const float4 v = ((const float4*)src)[j];
        t[(4 * j + 0) * CIN + ci] = (unsigned short)(__float_as_uint(v.x) >> 16);
        t[(4 * j + 1) * CIN + ci] = (unsigned short)(__float_as_uint(v.y) >> 16);
        t[(4 * j + 2) * CIN + ci] = (unsigned short)(__float_as_uint(v.z) >> 16);
        t[(4 * j + 3) * CIN + ci] = (unsigned short)(__float_as_uint(v.w) >> 16);
    }

    const uint4 z = make_uint4(0, 0, 0, 0);
    if (ci < 32) {
        const int side = ci >> 4;            // 0 = x'=0, 1 = x'=57
        const int j    = ci & 15;
        ((uint4*)(xp + ((size_t)n * XPIX + (y + 1) * XPW + side * 57) * CIN))[j] = z;
    }
    if (y == 0)
        for (int j = ci; j < 928; j += 128)  // row 0: 58*128 bf16 = 928 uint4
            ((uint4*)(xp + (size_t)n * XPIX * CIN))[j] = z;
    if (y == HH - 1)
        for (int j = ci; j < 928; j += 128)  // row 57
            ((uint4*)(xp + ((size_t)n * XPIX + 57 * XPW) * CIN))[j] = z;

    __syncthreads();

    uint4* dst = (uint4*)(xp + ((size_t)n * XPIX + (y + 1) * XPW + 1) * CIN);
    const uint4* lsrc = (const uint4*)t;
    #pragma unroll
    for (int j = 0; j < 7; ++j)
        dst[j * 128 + ci] = lsrc[j * 128 + ci];
}

// ---- pre-pass 2: w (co,ci,3,3) f32 -> Wt[tap][co][ci] bf16
__global__ __launch_bounds__(256) void prep_w(const float* __restrict__ w,
                                              __hip_bfloat16* __restrict__ wt) {
    const int co = blockIdx.x * 2 + (threadIdx.x >> 7);
    const int ci = threadIdx.x & 127;
    const float* src = w + (size_t)(co * CIN + ci) * 9;
    #pragma unroll
    for (int tp = 0; tp < 9; ++tp)
        wt[(size_t)tp * (COUT * CIN) + co * CIN + ci] = __float2bfloat16(src[tp]);
}

// ---- main: no-LDS implicit GEMM over taps; K = 9 taps * 128 ci = 1152 = 36 slabs of 32.
// Fragment addresses (R5-validated k-algebra with the LDS swizzle canceled out):
//   A (lane quad,l15):  Wt + tap*65536 + (cobase + wm*64 + mt*16 + l15)*256 + kq*64 + quad*16
//   B (lane quad,l15): xpad + pix(p)*256 + (r*58+sx)*256 + kq*64 + quad*16
// Each wave-load = 16 rows x 64 B contiguous segments. No __shared__, no __syncthreads.
__global__ __launch_bounds__(256, 4) void conv_main(
    const char* __restrict__ xpb,
    const char* __restrict__ wtb,
    const float* __restrict__ bias,
    float* __restrict__ out)
{
    const int tid  = threadIdx.x;
    const int l    = tid & 63;
    const int wv   = tid >> 6;
    const int wm   = wv & 1;
    const int wn   = wv >> 1;
    const int l15  = l & 15;
    const int quad = l >> 4;

    // XCD-pair swizzle (1568 = 16*98, bijective): blocks idx, idx+8 share bn.
    const int idx = blockIdx.x;
    const int bm  = (idx >> 3) & 1;
    const int bn  = (idx >> 4) * 8 + (idx & 7);
    const int pbase  = bn * 128;
    const int cobase = bm * 128;

    // per-lane fragment base addresses
    const char* ab[4];
    #pragma unroll
    for (int mt = 0; mt < 4; ++mt)
        ab[mt] = wtb + (size_t)(cobase + wm * 64 + mt * 16 + l15) * 256 + quad * 16;
    const char* bb[4];
    #pragma unroll
    for (int nt = 0; nt < 4; ++nt) {
        const int p   = pbase + wn * 64 + nt * 16 + l15;
        const int n   = p / HW;
        const int rem = p - n * HW;
        const int y   = rem / WW;
        const int x   = rem - y * WW;
        bb[nt] = xpb + (size_t)(n * XPIX + y * XPW + x) * 256 + quad * 16;
    }

    f32x4 acc[4][4];
    #pragma unroll
    for (int i = 0; i < 4; ++i)
        #pragma unroll
        for (int j = 0; j < 4; ++j)
            acc[i][j] = (f32x4){0.f, 0.f, 0.f, 0.f};

    // slab s: tap tp = s>>2 (shift r,sx), ci-quarter kq = s&3 (64 B within 256 B ci-row)
    #pragma unroll
    for (int s = 0; s < 36; ++s) {
        const int tp = s >> 2;
        const int kq = s & 3;
        const int r  = tp / 3;
        const int sx = tp - 3 * r;
        const unsigned wo = (unsigned)(tp * (COUT * CIN * 2) + kq * 64);
        const unsigned bo = (unsigned)((r * XPW + sx) * 256 + kq * 64);

        bf16x8 af[4], bf[4];
        #pragma unroll
        for (int mt = 0; mt < 4; ++mt)
            af[mt] = *(const bf16x8*)(ab[mt] + wo);
        #pragma unroll
        for (int nt = 0; nt < 4; ++nt)
            bf[nt] = *(const bf16x8*)(bb[nt] + bo);

        #pragma unroll
        for (int mt = 0; mt < 4; ++mt)
            #pragma unroll
            for (int nt = 0; nt < 4; ++nt)
                acc[mt][nt] = __builtin_amdgcn_mfma_f32_16x16x32_bf16(
                    af[mt], bf[nt], acc[mt][nt], 0, 0, 0);
    }

    // epilogue: D[m = quad*4+reg][n = l15]; out (N, C_out, H, W)
    #pragma unroll
    for (int nt = 0; nt < 4; ++nt) {
        const int pp = pbase + wn * 64 + nt * 16 + l15;
        const int n2 = pp / HW;
        const int r2 = pp - n2 * HW;
        float* ob = out + (size_t)n2 * (COUT * HW) + r2;
        #pragma unroll
        for (int mt = 0; mt < 4; ++mt) {
            const int co = cobase + wm * 64 + mt * 16 + quad * 4;
            const float4 bv = *(const float4*)(bias + co);
            f32x4 a = acc[mt][nt];
            ob[(size_t)(co + 0) * HW] = a[0] + bv.x;
            ob[(size_t)(co + 1) * HW] = a[1] + bv.y;
            ob[(size_t)(co + 2) * HW] = a[2] + bv.z;
            ob[(size_t)(co + 3) * HW] = a[3] + bv.w;
        }
    }
}

extern "C" void kernel_launch(void* const* d_in, const int* in_sizes, int n_in,
                              void* d_out, int out_size, void* d_ws, size_t ws_size,
                              hipStream_t stream) {
    const float* x = (const float*)d_in[0];
    const float* w = (const float*)d_in[1];
    const float* b = (const float*)d_in[2];
    char* ws = (char*)d_ws;                      // needs >= 28.2 MB
    __hip_bfloat16* xp = (__hip_bfloat16*)ws;
    __hip_bfloat16* wt = (__hip_bfloat16*)(ws + WT_OFF);

    prep_x<<<dim3(NIMG * HH), dim3(128), 0, stream>>>(x, xp);
    prep_w<<<dim3(128), dim3(256), 0, stream>>>(w, wt);
    conv_main<<<dim3((NP / 128) * 2), dim3(256), 0, stream>>>(
        (const char*)xp, (const char*)wt, b, (float*)d_out);
}

// Round 10
// 205.991 us; speedup vs baseline: 1.9162x; 1.9162x over previous
//
#include <hip/hip_runtime.h>
#include <hip/hip_bf16.h>

// Conv2d 3x3 s1p1: x(32,128,56,56) f32, w(256,128,3,3) f32, bias(256) -> (32,256,56,56) f32.
// R8: conv_main reverted to R5 VERBATIM (best measured: 75.6-77.7 us; R4/R6 pipelines and
// R7 no-LDS all regressed — LDS staging is the wave-to-wave amortizer, R7 proved the
// direct L1/L2 path is latency-bound at 260 us). This round attacks the stable ~130 us
// non-conv residual: prep_x's reads were wave-uncoalesced (lane=ci -> 12.5 KB lane stride,
// L1 reuse window 112 KB >> 32 KB). New prep_x: 16-lane groups span x (224 B contiguous
// per group), LDS transpose [ci][x] with stride 60 (8B-aligned b64 writes, conflict-light),
// output writes unchanged (already coalesced). prep_w unchanged.

#define CIN   128
#define HH    56
#define WW    56
#define COUT  256
#define HW    3136
#define NIMG  32
#define NP    (NIMG * HW)            // 100352 = 784 * 128
#define XPW   58
#define XPIX  (XPW * XPW)            // 3364
#define XPAD_BYTES (NIMG * XPIX * CIN * 2)   // 27,566,080
#define WT_OFF     XPAD_BYTES

typedef __bf16 bf16x8 __attribute__((ext_vector_type(8)));
typedef float  f32x4  __attribute__((ext_vector_type(4)));

#define GLD16(g, l) __builtin_amdgcn_global_load_lds( \
    (const __attribute__((address_space(1))) void*)(g), \
    (__attribute__((address_space(3))) void*)(l), 16, 0, 0)

// ---- pre-pass 1: x NCHW f32 -> xpad NHWC bf16 with 1-px halo; writes own halo zeros.
// Read phase: 16 iters; iter g covers ci = g*8 + (tid>>4), xseg = tid&15 (<14 active):
// 16-lane group reads 14 consecutive float4 (224 B contiguous) of one ci-row. Transpose
// via LDS t2[ci][x] (ushort, row stride 60 -> 8B-aligned ushort4 writes, banks spread).
// Write phase: identical mapping to the validated original (uint4 u = j*128+tid covers
// pixel p = j*8 + (tid>>4), ci-slice c0 = (tid&15)*8), gathering 8 ushorts per uint4.
__global__ __launch_bounds__(128) void prep_x(const float* __restrict__ x,
                                              __hip_bfloat16* __restrict__ xp) {
    __shared__ unsigned short t2[128 * 60];  // [ci][x], stride 60, 15360 B
    const int b   = blockIdx.x;              // 32*56
    const int n   = b / HH;
    const int y   = b - n * HH;
    const int tid = threadIdx.x;             // 0..127
    const int xseg = tid & 15;               // 0..15 (active < 14)
    const int cio  = tid >> 4;               // 0..7

    if (xseg < 14) {
        const float* base = x + (size_t)(n * CIN) * HW + y * WW + xseg * 4;
        #pragma unroll
        for (int g = 0; g < 16; ++g) {
            const int ci = g * 8 + cio;
            const float4 v = *(const float4*)(base + (size_t)ci * HW);
            ushort4 u;
            u.x = (unsigned short)(__float_as_uint(v.x) >> 16);
            u.y = (unsigned short)(__float_as_uint(v.y) >> 16);
            u.z = (unsigned short)(__float_as_uint(v.z) >> 16);
            u.w = (unsigned short)(__float_as_uint(v.w) >> 16);
            *(ushort4*)&t2[ci * 60 + xseg * 4] = u;
        }
    }

    // halo: left/right column of this row, plus full top/bottom rows from edge blocks
    const uint4 z = make_uint4(0, 0, 0, 0);
    if (tid < 32) {
        const int side = tid >> 4;           // 0 = x'=0, 1 = x'=57
        const int j    = tid & 15;
        ((uint4*)(xp + ((size_t)n * XPIX + (y + 1) * XPW + side * 57) * CIN))[j] = z;
    }
    if (y == 0)
        for (int j = tid; j < 928; j += 128) // row 0: 58*128 bf16 = 928 uint4
            ((uint4*)(xp + (size_t)n * XPIX * CIN))[j] = z;
    if (y == HH - 1)
        for (int j = tid; j < 928; j += 128) // row 57
            ((uint4*)(xp + ((size_t)n * XPIX + 57 * XPW) * CIN))[j] = z;

    __syncthreads();

    // coalesced interior write: 56 pixels * 256 B contiguous = 896 uint4
    uint4* dst = (uint4*)(xp + ((size_t)n * XPIX + (y + 1) * XPW + 1) * CIN);
    const int c0   = (tid & 15) * 8;
    const int prow = tid >> 4;               // 0..7
    #pragma unroll
    for (int j = 0; j < 7; ++j) {
        const int p = j * 8 + prow;          // pixel 0..55
        uint4 o;
        o.x = (unsigned)t2[(c0 + 0) * 60 + p] | ((unsigned)t2[(c0 + 1) * 60 + p] << 16);
        o.y = (unsigned)t2[(c0 + 2) * 60 + p] | ((unsigned)t2[(c0 + 3) * 60 + p] << 16);
        o.z = (unsigned)t2[(c0 + 4) * 60 + p] | ((unsigned)t2[(c0 + 5) * 60 + p] << 16);
        o.w = (unsigned)t2[(c0 + 6) * 60 + p] | ((unsigned)t2[(c0 + 7) * 60 + p] << 16);
        dst[j * 128 + tid] = o;
    }
}

// ---- pre-pass 2: w (co,ci,3,3) f32 -> Wt[tap][co][ci] bf16
__global__ __launch_bounds__(256) void prep_w(const float* __restrict__ w,
                                              __hip_bfloat16* __restrict__ wt) {
    const int co = blockIdx.x * 2 + (threadIdx.x >> 7);
    const int ci = threadIdx.x & 127;
    const float* src = w + (size_t)(co * CIN + ci) * 9;
    #pragma unroll
    for (int tp = 0; tp < 9; ++tp)
        wt[(size_t)tp * (COUT * CIN) + co * CIN + ci] = __float2bfloat16(src[tp]);
}

// ---- main (R5 verbatim): implicit GEMM over taps; K = 1152 = 18 stages of 64.
// LDS: A 16KB + B 16KB = 32 KB single-buffered -> 5 blocks/CU. Rows are 128 B (8 segs).
// Swizzle: LDS seg of row R holds global seg s^(R&7); store: gseg=(l&7)^(l>>3);
// read: seg = kslice ^ (l15&7).
__global__ __launch_bounds__(256) void conv_main(
    const char* __restrict__ xpb,
    const char* __restrict__ wtb,
    const float* __restrict__ bias,
    float* __restrict__ out)
{
    __shared__ __align__(16) char L[32768];  // A: [0,16384), B: [16384,32768)

    const int tid  = threadIdx.x;
    const int l    = tid & 63;
    const int wv   = tid >> 6;
    const int wm   = wv & 1;
    const int wn   = wv >> 1;
    const int l15  = l & 15;
    const int quad = l >> 4;

    // XCD-pair swizzle: blocks idx and idx+8 (same XCD under %8 round-robin) share bn.
    const int idx = blockIdx.x;
    const int bm  = (idx >> 3) & 1;
    const int bn  = (idx >> 4) * 8 + (idx & 7);
    const int pbase  = bn * 128;
    const int cobase = bm * 128;

    // staging: chunk c = wv*4+j covers rows c*8..c*8+7 (8 rows x 128 B = 1 KB);
    // lane -> row c*8 + (l>>3), LDS seg l&7, global seg (l&7)^(l>>3)  (lane-only).
    const int gseg = (l & 7) ^ (l >> 3);
    unsigned aoff[4], boff[4];
    #pragma unroll
    for (int j = 0; j < 4; ++j) {
        const int c   = wv * 4 + j;
        const int row = c * 8 + (l >> 3);
        aoff[j] = (unsigned)((cobase + row) * 256 + gseg * 16);
        const int p   = pbase + row;
        const int n   = p / HW;
        const int rem = p - n * HW;
        const int y   = rem / WW;
        const int x   = rem - y * WW;
        boff[j] = (unsigned)((n * XPIX + y * XPW + x) * 256 + gseg * 16);
    }

    f32x4 acc[4][4];
    #pragma unroll
    for (int i = 0; i < 4; ++i)
        #pragma unroll
        for (int j = 0; j < 4; ++j)
            acc[i][j] = (f32x4){0.f, 0.f, 0.f, 0.f};

    // stage s: tap t = s>>1, ci-half h = s&1 (bytes h*128 within each 256 B ci-row)
    #pragma unroll
    for (int s = 0; s < 18; ++s) {
        const int t  = s >> 1;
        const int h  = s & 1;
        const int r  = t / 3;
        const int sx = t - 3 * r;
        const unsigned wo = (unsigned)(t * (COUT * CIN * 2) + h * 128);   // Wt tap plane
        const unsigned bo = (unsigned)((r * XPW + sx) * 256 + h * 128);   // xpad tap shift

        __syncthreads();
        #pragma unroll
        for (int j = 0; j < 4; ++j) {
            const int c = wv * 4 + j;
            GLD16(wtb + wo + aoff[j], L + c * 1024);
            GLD16(xpb + bo + boff[j], L + 16384 + c * 1024);
        }
        __syncthreads();

        #pragma unroll
        for (int kg = 0; kg < 2; ++kg) {
            bf16x8 af[4], bfr[4];
            const int segoff = ((kg * 4 + quad) ^ (l15 & 7)) << 4;
            #pragma unroll
            for (int mt = 0; mt < 4; ++mt) {
                const int row = wm * 64 + mt * 16 + l15;
                af[mt] = *(const bf16x8*)(L + row * 128 + segoff);
            }
            #pragma unroll
            for (int nt = 0; nt < 4; ++nt) {
                const int row = wn * 64 + nt * 16 + l15;
                bfr[nt] = *(const bf16x8*)(L + 16384 + row * 128 + segoff);
            }
            #pragma unroll
            for (int mt = 0; mt < 4; ++mt)
                #pragma unroll
                for (int nt = 0; nt < 4; ++nt)
                    acc[mt][nt] = __builtin_amdgcn_mfma_f32_16x16x32_bf16(
                        af[mt], bfr[nt], acc[mt][nt], 0, 0, 0);
        }
    }

    // epilogue: D[m = quad*4+reg][n = l15]; out (N, C_out, H, W)
    #pragma unroll
    for (int nt = 0; nt < 4; ++nt) {
        const int pp = pbase + wn * 64 + nt * 16 + l15;
        const int n2 = pp / HW;
        const int r2 = pp - n2 * HW;
        float* ob = out + (size_t)n2 * (COUT * HW) + r2;
        #pragma unroll
        for (int mt = 0; mt < 4; ++mt) {
            const int co = cobase + wm * 64 + mt * 16 + quad * 4;
            const float4 bv = *(const float4*)(bias + co);
            f32x4 a = acc[mt][nt];
            ob[(size_t)(co + 0) * HW] = a[0] + bv.x;
            ob[(size_t)(co + 1) * HW] = a[1] + bv.y;
            ob[(size_t)(co + 2) * HW] = a[2] + bv.z;
            ob[(size_t)(co + 3) * HW] = a[3] + bv.w;
        }
    }
}

extern "C" void kernel_launch(void* const* d_in, const int* in_sizes, int n_in,
                              void* d_out, int out_size, void* d_ws, size_t ws_size,
                              hipStream_t stream) {
    const float* x = (const float*)d_in[0];
    const float* w = (const float*)d_in[1];
    const float* b = (const float*)d_in[2];
    char* ws = (char*)d_ws;                      // needs >= 28.2 MB
    __hip_bfloat16* xp = (__hip_bfloat16*)ws;
    __hip_bfloat16* wt = (__hip_bfloat16*)(ws + WT_OFF);

    prep_x<<<dim3(NIMG * HH), dim3(128), 0, stream>>>(x, xp);
    prep_w<<<dim3(128), dim3(256), 0, stream>>>(w, wt);
    conv_main<<<dim3((NP / 128) * 2), dim3(256), 0, stream>>>(
        (const char*)xp, (const char*)wt, b, (float*)d_out);
}